// Round 12
// baseline (133.994 us; speedup 1.0000x reference)
//
#include <hip/hip_runtime.h>
#include <stdint.h>

typedef __attribute__((ext_vector_type(8))) short bf16x8;
typedef __attribute__((ext_vector_type(4))) float f32x4;
typedef __attribute__((ext_vector_type(4))) unsigned short u16x4;
typedef unsigned short u16;

#define NBATCH 4
#define SEQ    4096
#define CIN    512
#define HD     64
#define OC     576      // f32 elements per out row
#define NROW   (NBATCH * SEQ)
#define KVB    262144   // u16 elements per batch in K / V tiled buffers

__device__ __forceinline__ float b2f(u16 u) {
    union { uint32_t i; float f; } w; w.i = ((uint32_t)u) << 16; return w.f;
}
__device__ __forceinline__ u16 f2b(float f) {
    union { float f; uint32_t i; } w; w.f = f;
    uint32_t r = w.i + 0x7fffu + ((w.i >> 16) & 1u);
    return (u16)(r >> 16);
}
// pack two f32 -> two bf16 (RTNE) in one VGPR: lo = a, hi = b
__device__ __forceinline__ uint32_t cvtpk_bf16(float a, float b) {
    uint32_t r;
    asm("v_cvt_pk_bf16_f32 %0, %1, %2" : "=v"(r) : "v"(a), "v"(b));
    return r;
}

// ---------------------------------------------------------------------------
// Kernel 1: transpose f32 weights into FRAGMENT-MAJOR bf16 tiles:
// wtt[frag = nt*16 + c][lane = quad*16 + m][8] (unchanged from R11).
// ---------------------------------------------------------------------------
__global__ void prep_wt(const float* __restrict__ Wq, const float* __restrict__ Wk,
                        const float* __restrict__ Wv, u16* __restrict__ wt) {
    int row = blockIdx.x;            // 0..191
    int g = row >> 6, j = row & 63;
    const float* W = (g == 0) ? Wq : (g == 1) ? Wk : Wv;
    int nt = row >> 4, m = row & 15;
    for (int k = threadIdx.x; k < CIN; k += blockDim.x) {
        int c = k >> 5, qd = (k >> 3) & 3, jj = k & 7;
        size_t off = ((size_t)(nt * 16 + c) * 64 + qd * 16 + m) * 8 + jj;
        wt[off] = f2b(W[k * HD + j]);
    }
}

// ---------------------------------------------------------------------------
// Kernel 2: QKV projection (unchanged from R11, ~22.5 us).
// Fragment-major wt (dense 1KB loads), 32-row blocks / 64KB swizzled panel
// via global_load_lds, 3 nt x 2 row-tiles per wave, cvt_pk convert,
// x-copy from panel. Q pre-scaled by 0.125*log2(e). K/V stores in attn's
// fragment-major tiled layouts.
// ---------------------------------------------------------------------------
__global__ __launch_bounds__(256) void proj(
    const float* __restrict__ x, const u16* __restrict__ wt,
    const float* __restrict__ bq, const float* __restrict__ bk, const float* __restrict__ bv,
    u16* __restrict__ qb, u16* __restrict__ kbuf, u16* __restrict__ vtb,
    float* __restrict__ out)
{
    __shared__ __align__(16) float xs[32 * 512];   // 64 KiB x-panel (swizzled)

    int tid = threadIdx.x;
    int lane = tid & 63, w = tid >> 6;   // 4 waves
    int m = lane & 15, quad = lane >> 4;
    int r0b = blockIdx.x * 32;           // first global row of this block

    // ---- stage x: 16 rounds of global_load_lds (R7 scheme, verified) ----
    {
        int rw = w >> 1;                  // wave-uniform row parity
        int pp = (w & 1) * 64 + lane;     // phys granule within row
#pragma unroll
        for (int k = 0; k < 16; k++) {
            int r = k * 2 + rw;
            int g = pp ^ (r & 15);
            const float* src = x + (size_t)(r0b + r) * CIN + g * 4;
            float* dst = xs + (size_t)(k * 256 + w * 64 + lane) * 4;
            __builtin_amdgcn_global_load_lds(
                (const __attribute__((address_space(1))) void*)src,
                (__attribute__((address_space(3))) void*)dst, 16, 0, 0);
        }
    }
    __syncthreads();   // drains vmcnt -> panel ready

    int ntb = w * 3;                      // this wave's 3 output tiles

    f32x4 acc0[3], acc1[3];               // [nt] for row-tile 0 / 1
#pragma unroll
    for (int i = 0; i < 3; i++) {
        acc0[i] = (f32x4){0.f, 0.f, 0.f, 0.f};
        acc1[i] = (f32x4){0.f, 0.f, 0.f, 0.f};
    }

    const float* xrow0 = xs + (size_t)m * 512;          // tile0 row (r&15 = m)
    const float* xrow1 = xs + (size_t)(16 + m) * 512;   // tile1 row (r&15 = m)

#pragma unroll
    for (int c = 0; c < 16; c++) {
        int L0 = c * 8 + quad * 2;           // logical granule of this lane's 8 floats
        f32x4 va0 = *(const f32x4*)(xrow0 + (size_t)((L0 ^ m) * 4));
        f32x4 vb0 = *(const f32x4*)(xrow0 + (size_t)(((L0 + 1) ^ m) * 4));
        f32x4 va1 = *(const f32x4*)(xrow1 + (size_t)((L0 ^ m) * 4));
        f32x4 vb1 = *(const f32x4*)(xrow1 + (size_t)(((L0 + 1) ^ m) * 4));
        bf16x8 a0, a1;
        {
            uint32_t* p0 = (uint32_t*)&a0;
            p0[0] = cvtpk_bf16(va0[0], va0[1]);
            p0[1] = cvtpk_bf16(va0[2], va0[3]);
            p0[2] = cvtpk_bf16(vb0[0], vb0[1]);
            p0[3] = cvtpk_bf16(vb0[2], vb0[3]);
            uint32_t* p1 = (uint32_t*)&a1;
            p1[0] = cvtpk_bf16(va1[0], va1[1]);
            p1[1] = cvtpk_bf16(va1[2], va1[3]);
            p1[2] = cvtpk_bf16(vb1[0], vb1[1]);
            p1[3] = cvtpk_bf16(vb1[2], vb1[3]);
        }
#pragma unroll
        for (int t = 0; t < 3; t++) {
            int nt = ntb + t;
            // dense 1KB frag load: wtt[frag = nt*16+c][lane][8]
            bf16x8 b = *(const bf16x8*)(wt + ((size_t)(nt * 16 + c) * 64 + quad * 16 + m) * 8);
            acc0[t] = __builtin_amdgcn_mfma_f32_16x16x32_bf16(a0, b, acc0[t], 0, 0, 0);
            acc1[t] = __builtin_amdgcn_mfma_f32_16x16x32_bf16(a1, b, acc1[t], 0, 0, 0);
        }
    }

    // ---- x-copy from the LDS panel (R7 scheme) ----
#pragma unroll
    for (int k = 0; k < 16; k++) {
        int G = k * 256 + tid;
        int r = G >> 7, p = G & 127;
        f32x4 v = *(const f32x4*)(xs + (size_t)G * 4);
        int col = (p ^ (r & 15)) * 4;
        *(f32x4*)(out + (size_t)(r0b + r) * OC + col) = v;
    }

    const float SCQ = 0.125f * 1.44269504088896f;   // scale * log2(e), baked into Q

#pragma unroll
    for (int tt = 0; tt < 2; tt++) {
        int r0 = r0b + tt * 16;
        int n  = r0 >> 12;          // batch
        int tl = r0 & (SEQ - 1);    // t within batch (16-aligned)
#pragma unroll
        for (int t = 0; t < 3; t++) {
            f32x4 acc = tt ? acc1[t] : acc0[t];
            int nt = ntb + t;                 // 0..11, wave-uniform
            int bi = (nt & 3) * 16 + m;       // column within its 64-wide matrix
            if (nt < 4) {
                float biasq = bq[bi];
#pragma unroll
                for (int reg = 0; reg < 4; reg++) {
                    size_t r = (size_t)(r0 + quad * 4 + reg);
                    qb[r * HD + bi] = f2b((acc[reg] + biasq) * SCQ);
                }
            } else if (nt < 8) {
                // K tiled store: [n][tl/16][bi>>3][key%16][bi&7]
                float biask = bk[bi];
                u16* kbase = kbuf + (size_t)n * KVB
                           + (((size_t)(tl >> 4) * 8 + (bi >> 3)) * 16) * 8 + (bi & 7);
#pragma unroll
                for (int reg = 0; reg < 4; reg++) {
                    int mkey = quad * 4 + reg;
                    kbase[(size_t)mkey * 8] = f2b(acc[reg] + biask);
                }
            } else {
                // V tiled store: [n][bi>>4][key/32][(key>>3)&3][bi&15][key&7]
                float biasv = bv[bi];
                u16x4 pk;
#pragma unroll
                for (int reg = 0; reg < 4; reg++) pk[reg] = f2b(acc[reg] + biasv);
                int key0 = tl + quad * 4;
                size_t off = ((((size_t)(bi >> 4) * 128 + (key0 >> 5)) * 4
                               + ((key0 >> 3) & 3)) * 16 + (bi & 15)) * 8 + (key0 & 7);
                *(u16x4*)(vtb + (size_t)n * KVB + off) = pk;
            }
        }
    }
}

// ---------------------------------------------------------------------------
// Kernel 3: causal flash attention. R12: ANTITHETIC BLOCK PAIRING (only
// change from R11). Diagnosis: per-visit cost ~783 cy; under the old LPT
// map (jj = 127 - sub) the two blocks co-resident on a CU were
// (heavy ~127-c/4, medium ~63-c/4) -> CU0 carries ~95 visits vs avg 65,
// and 95 x 783 cy = 31.0 us = EXACTLY the measured wall time. Fix: low
// half of the grid takes heavy tiles jj = 127-g, high half the antithetic
// light tiles jj = g (same g per (xcd,li)) -> each CU's resident pair sums
// to ~65.5 visits, uniform. XCD-batch affinity and coverage preserved;
// everything else (loop body, layouts, LDS, numerics) byte-identical:
// dense fragment-major K/V loads, union LDS, 2 q-chains, Q pre-scaled,
// l via ones-MFMA, defer-max THR=8, cvt_pk packing.
// ---------------------------------------------------------------------------
__global__ __launch_bounds__(512, 2) void attn(
    const u16* __restrict__ qb, const u16* __restrict__ kbuf,
    const u16* __restrict__ vtb, float* __restrict__ out)
{
    __shared__ __align__(16) union {
        short p[8][16 * 72];     // P^T per wave (18.4 KiB) - visit phase
        float o[8][16][68];      // O^T partials (34.8 KiB) - merge phase
    } lu;
    __shared__ float ldsm[8][16];                        // m partials [w][t]
    __shared__ float ldsl[8][16];                        // l partials [w][t]

    int tid = threadIdx.x;
    int lane = tid & 63, w = tid >> 6;   // 8 waves
    int m = lane & 15, quad = lane >> 4;

    int idx = blockIdx.x;                 // 0..511
    int xcd = idx & 7;                    // HW round-robins blockIdx across XCDs
    int batch = xcd >> 1;                 // 2 XCDs per batch
    int li = (idx >> 3) & 31;             // 0..31 within grid half
    int g  = li * 2 + (xcd & 1);          // 0..63
    int jj = (idx < 256) ? (127 - g) : g; // antithetic pair lands on same CU
    int t0 = jj * 32;
    int nkb = (jj >> 1) + 1;              // 64-key blocks needed
    int lastkb = nkb - 1;

    const u16* kpb = kbuf + (size_t)batch * KVB;   // tiled K base
    const u16* vpb = vtb + (size_t)batch * KVB;    // tiled V base

    bf16x8 ones;
#pragma unroll
    for (int i = 0; i < 8; i++) ones[i] = (short)0x3F80;   // bf16 1.0

    const u16* qpb = qb + (size_t)(batch * SEQ + t0 + m) * HD + quad * 8;
    bf16x8 q0[2], q1[2];
#pragma unroll
    for (int q = 0; q < 2; q++) {
        q0[q] = *(const bf16x8*)(qpb + (size_t)(q * 16) * HD);
        q1[q] = *(const bf16x8*)(qpb + (size_t)(q * 16) * HD + 32);
    }

    float mst[2];
    f32x4 o[2][4], ol[2];
#pragma unroll
    for (int q = 0; q < 2; q++) {
        mst[q] = -1e30f;
        ol[q] = (f32x4){0.f, 0.f, 0.f, 0.f};
#pragma unroll
        for (int nt = 0; nt < 4; nt++) o[q][nt] = (f32x4){0.f, 0.f, 0.f, 0.f};
    }

    int cnt = (nkb > w) ? ((nkb - w + 7) >> 3) : 0;
    int kb = w;
    short* pw = &lu.p[w][0];

    // preload K A-frags for first kb (in-bounds even when cnt==0: kb<=7)
    bf16x8 k0[4], k1[4];
#pragma unroll
    for (int st = 0; st < 4; st++) {
        k0[st] = *(const bf16x8*)(kpb + (size_t)((kb * 4 + st) * 8 + quad) * 128 + m * 8);
        k1[st] = *(const bf16x8*)(kpb + (size_t)((kb * 4 + st) * 8 + quad + 4) * 128 + m * 8);
    }

    for (int it = 0; it < cnt; it++, kb += 8) {
        int s0 = kb * 64;
        bool diag = (kb == lastkb);

        // V loads (dense 1KB frag txns), issued early, consumed after softmax
        bf16x8 vf0[4], vf1[4];
#pragma unroll
        for (int nt = 0; nt < 4; nt++) {
            vf0[nt] = *(const bf16x8*)(vpb + (size_t)((nt * 128 + (s0 >> 5)) * 4 + quad) * 128 + m * 8);
            vf1[nt] = *(const bf16x8*)(vpb + (size_t)((nt * 128 + (s0 >> 5) + 1) * 4 + quad) * 128 + m * 8);
        }

        // S^T = K Q^T for both q sub-tiles (scores pre-scaled via Q)
        f32x4 s[2][4];
#pragma unroll
        for (int q = 0; q < 2; q++)
#pragma unroll
            for (int st = 0; st < 4; st++) {
                f32x4 a = (f32x4){0.f, 0.f, 0.f, 0.f};
                a = __builtin_amdgcn_mfma_f32_16x16x32_bf16(k0[st], q0[q], a, 0, 0, 0);
                a = __builtin_amdgcn_mfma_f32_16x16x32_bf16(k1[st], q1[q], a, 0, 0, 0);
                s[q][st] = a;
            }

        // last K use done: prefetch next key-block for this wave
        if (it + 1 < cnt) {
            int kn = kb + 8;
#pragma unroll
            for (int st = 0; st < 4; st++) {
                k0[st] = *(const bf16x8*)(kpb + (size_t)((kn * 4 + st) * 8 + quad) * 128 + m * 8);
                k1[st] = *(const bf16x8*)(kpb + (size_t)((kn * 4 + st) * 8 + quad + 4) * 128 + m * 8);
            }
        }

        // causal mask only on the diagonal block (wave-uniform branch)
        if (diag) {
#pragma unroll
            for (int q = 0; q < 2; q++)
#pragma unroll
                for (int st = 0; st < 4; st++)
#pragma unroll
                    for (int r = 0; r < 4; r++) {
                        int key = s0 + st * 16 + quad * 4 + r;
                        if (key > t0 + q * 16 + m) s[q][st][r] = -1e30f;
                    }
        }

        // softmax + P^T pack + PV, q-chains share one P buffer (per wave)
        bf16x8 pf0[2], pf1[2];
#pragma unroll
        for (int q = 0; q < 2; q++) {
            float mx = -1e30f;
#pragma unroll
            for (int st = 0; st < 4; st++) {
                float a01 = fmaxf(s[q][st][0], s[q][st][1]);
                float a23 = fmaxf(s[q][st][2], s[q][st][3]);
                mx = fmaxf(mx, fmaxf(a01, a23));
            }
            mx = fmaxf(mx, __shfl_xor(mx, 16, 64));
            mx = fmaxf(mx, __shfl_xor(mx, 32, 64));

            // defer-max: only rescale when max grew past threshold
            if (__any(mx > mst[q] + 8.0f)) {
                float mn = fmaxf(mst[q], mx);
                float al = exp2f(mst[q] - mn);
#pragma unroll
                for (int nt = 0; nt < 4; nt++)
#pragma unroll
                    for (int r = 0; r < 4; r++) o[q][nt][r] *= al;
                ol[q][0] *= al;   // only reg 0 of ol is ever read
                mst[q] = mn;
            }

#pragma unroll
            for (int st = 0; st < 4; st++) {
                float e0 = exp2f(s[q][st][0] - mst[q]);
                float e1 = exp2f(s[q][st][1] - mst[q]);
                float e2 = exp2f(s[q][st][2] - mst[q]);
                float e3 = exp2f(s[q][st][3] - mst[q]);
                uint2 pk2;
                pk2.x = cvtpk_bf16(e0, e1);
                pk2.y = cvtpk_bf16(e2, e3);
                *(uint2*)(pw + m * 72 + st * 16 + quad * 4) = pk2;
            }
            __asm__ volatile("" ::: "memory");   // pack-writes before frag-reads
            pf0[q] = *(const bf16x8*)(pw + m * 72 + quad * 8);
            pf1[q] = *(const bf16x8*)(pw + m * 72 + 32 + quad * 8);
            __asm__ volatile("" ::: "memory");   // frag-reads before next pack
        }

#pragma unroll
        for (int q = 0; q < 2; q++) {
            // O^T += V^T P^T ; l += ones . P^T (replaces VALU sum-reduce)
#pragma unroll
            for (int nt = 0; nt < 4; nt++) {
                o[q][nt] = __builtin_amdgcn_mfma_f32_16x16x32_bf16(vf0[nt], pf0[q], o[q][nt], 0, 0, 0);
                o[q][nt] = __builtin_amdgcn_mfma_f32_16x16x32_bf16(vf1[nt], pf1[q], o[q][nt], 0, 0, 0);
            }
            ol[q] = __builtin_amdgcn_mfma_f32_16x16x32_bf16(ones, pf0[q], ol[q], 0, 0, 0);
            ol[q] = __builtin_amdgcn_mfma_f32_16x16x32_bf16(ones, pf1[q], ol[q], 0, 0, 0);
        }
    }

    // all waves done with lu.p before lu.o is written (union safety)
    __syncthreads();

    // merge 8 wave-partials per q sub-tile (waves with cnt==0 publish
    // m=-1e30, l=0, O=0 -> zero weight; wave 0 always has work)
#pragma unroll
    for (int q = 0; q < 2; q++) {
        if (quad == 0) { ldsm[w][m] = mst[q]; ldsl[w][m] = ol[q][0]; }
#pragma unroll
        for (int nt = 0; nt < 4; nt++)
            *(f32x4*)&lu.o[w][m][nt * 16 + quad * 4] = o[q][nt];
        __syncthreads();

        if (tid < 256) {
            int t = tid >> 4, vg = tid & 15;
            float mmax = -1e30f;
#pragma unroll
            for (int u = 0; u < 8; u++) mmax = fmaxf(mmax, ldsm[u][t]);
            float L = 0.f;
            f32x4 acc = (f32x4){0.f, 0.f, 0.f, 0.f};
#pragma unroll
            for (int u = 0; u < 8; u++) {
                float c = exp2f(ldsm[u][t] - mmax);
                L += ldsl[u][t] * c;
                f32x4 ov = *(const f32x4*)&lu.o[u][t][vg * 4];
#pragma unroll
                for (int i2 = 0; i2 < 4; i2++) acc[i2] += ov[i2] * c;
            }
            float inv = 1.0f / L;
            f32x4 res;
#pragma unroll
            for (int i2 = 0; i2 < 4; i2++) res[i2] = acc[i2] * inv;
            *(f32x4*)(out + (size_t)(batch * SEQ + t0 + q * 16 + t) * OC + CIN + vg * 4) = res;
        }
        __syncthreads();   // lu.o reused by next q
    }
}

// ---------------------------------------------------------------------------
extern "C" void kernel_launch(void* const* d_in, const int* in_sizes, int n_in,
                              void* d_out, int out_size, void* d_ws, size_t ws_size,
                              hipStream_t stream) {
    const float* x  = (const float*)d_in[0];
    const float* Wq = (const float*)d_in[1];
    const float* bq = (const float*)d_in[2];
    const float* Wk = (const float*)d_in[3];
    const float* bk = (const float*)d_in[4];
    const float* Wv = (const float*)d_in[5];
    const float* bv = (const float*)d_in[6];
    float* out = (float*)d_out;

    u16* ws  = (u16*)d_ws;
    u16* wt  = ws;                          // tiled wt: [192 frags][64 lanes][8]
    u16* qb  = ws + 131072;                 // 16384*64 = 1M elems
    u16* kb  = qb + 16384 * 64;             // tiled K: [4][256tiles][8][16][8]
    u16* vtb = kb + 16384 * 64;             // tiled V: [4][4][128][4][16][8]

    prep_wt<<<dim3(192), dim3(256), 0, stream>>>(Wq, Wk, Wv, wt);
    proj<<<dim3(512), dim3(256), 0, stream>>>(x, wt, bq, bk, bv, qb, kb, vtb, out);
    attn<<<dim3(512), dim3(512), 0, stream>>>(qb, kb, vtb, out);
}

// Round 13
// 127.518 us; speedup vs baseline: 1.0508x; 1.0508x over previous
//
#include <hip/hip_runtime.h>
#include <stdint.h>

typedef __attribute__((ext_vector_type(8))) short bf16x8;
typedef __attribute__((ext_vector_type(4))) float f32x4;
typedef __attribute__((ext_vector_type(4))) unsigned short u16x4;
typedef unsigned short u16;

#define NBATCH 4
#define SEQ    4096
#define CIN    512
#define HD     64
#define OC     576      // f32 elements per out row
#define NROW   (NBATCH * SEQ)
#define KVB    262144   // u16 elements per batch in K / V tiled buffers

__device__ __forceinline__ float b2f(u16 u) {
    union { uint32_t i; float f; } w; w.i = ((uint32_t)u) << 16; return w.f;
}
__device__ __forceinline__ u16 f2b(float f) {
    union { float f; uint32_t i; } w; w.f = f;
    uint32_t r = w.i + 0x7fffu + ((w.i >> 16) & 1u);
    return (u16)(r >> 16);
}
// pack two f32 -> two bf16 (RTNE) in one VGPR: lo = a, hi = b
__device__ __forceinline__ uint32_t cvtpk_bf16(float a, float b) {
    uint32_t r;
    asm("v_cvt_pk_bf16_f32 %0, %1, %2" : "=v"(r) : "v"(a), "v"(b));
    return r;
}

// ---------------------------------------------------------------------------
// Kernel 1: transpose f32 weights into FRAGMENT-MAJOR bf16 tiles:
// wtt[frag = nt*16 + c][lane = quad*16 + m][8] (unchanged from R11).
// ---------------------------------------------------------------------------
__global__ void prep_wt(const float* __restrict__ Wq, const float* __restrict__ Wk,
                        const float* __restrict__ Wv, u16* __restrict__ wt) {
    int row = blockIdx.x;            // 0..191
    int g = row >> 6, j = row & 63;
    const float* W = (g == 0) ? Wq : (g == 1) ? Wk : Wv;
    int nt = row >> 4, m = row & 15;
    for (int k = threadIdx.x; k < CIN; k += blockDim.x) {
        int c = k >> 5, qd = (k >> 3) & 3, jj = k & 7;
        size_t off = ((size_t)(nt * 16 + c) * 64 + qd * 16 + m) * 8 + jj;
        wt[off] = f2b(W[k * HD + j]);
    }
}

// ---------------------------------------------------------------------------
// Kernel 2: QKV projection. R13 = R11 + Q/K STORE REPACK via LDS.
// Diagnosis: Q and K epilogue stores were ~4096 scalar 2B scattered stores
// per block (Q stride-128B rows; K stride-16B frag slots) -> store-issue
// and L2 write-merge overhead. Fix: after the x-copy frees the 64KB panel,
// scatter Q/K (bias applied, bf16) into LDS [32][64] tiles, barrier, then
// 512 coalesced 16B vector stores writing the exact same final layouts.
// V stores were already contiguous (u16x4) - unchanged.
// Everything else identical to R11: fragment-major wt (dense 1KB loads),
// 32-row blocks / 64KB swizzled panel via global_load_lds, 3 nt x 2
// row-tiles per wave, cvt_pk convert, Q pre-scaled by 0.125*log2(e).
// ---------------------------------------------------------------------------
__global__ __launch_bounds__(256) void proj(
    const float* __restrict__ x, const u16* __restrict__ wt,
    const float* __restrict__ bq, const float* __restrict__ bk, const float* __restrict__ bv,
    u16* __restrict__ qb, u16* __restrict__ kbuf, u16* __restrict__ vtb,
    float* __restrict__ out)
{
    __shared__ __align__(16) float xs[32 * 512];   // 64 KiB x-panel (swizzled)

    int tid = threadIdx.x;
    int lane = tid & 63, w = tid >> 6;   // 4 waves
    int m = lane & 15, quad = lane >> 4;
    int r0b = blockIdx.x * 32;           // first global row of this block

    // ---- stage x: 16 rounds of global_load_lds (R7 scheme, verified) ----
    {
        int rw = w >> 1;                  // wave-uniform row parity
        int pp = (w & 1) * 64 + lane;     // phys granule within row
#pragma unroll
        for (int k = 0; k < 16; k++) {
            int r = k * 2 + rw;
            int g = pp ^ (r & 15);
            const float* src = x + (size_t)(r0b + r) * CIN + g * 4;
            float* dst = xs + (size_t)(k * 256 + w * 64 + lane) * 4;
            __builtin_amdgcn_global_load_lds(
                (const __attribute__((address_space(1))) void*)src,
                (__attribute__((address_space(3))) void*)dst, 16, 0, 0);
        }
    }
    __syncthreads();   // drains vmcnt -> panel ready

    int ntb = w * 3;                      // this wave's 3 output tiles

    f32x4 acc0[3], acc1[3];               // [nt] for row-tile 0 / 1
#pragma unroll
    for (int i = 0; i < 3; i++) {
        acc0[i] = (f32x4){0.f, 0.f, 0.f, 0.f};
        acc1[i] = (f32x4){0.f, 0.f, 0.f, 0.f};
    }

    const float* xrow0 = xs + (size_t)m * 512;          // tile0 row (r&15 = m)
    const float* xrow1 = xs + (size_t)(16 + m) * 512;   // tile1 row (r&15 = m)

#pragma unroll
    for (int c = 0; c < 16; c++) {
        int L0 = c * 8 + quad * 2;           // logical granule of this lane's 8 floats
        f32x4 va0 = *(const f32x4*)(xrow0 + (size_t)((L0 ^ m) * 4));
        f32x4 vb0 = *(const f32x4*)(xrow0 + (size_t)(((L0 + 1) ^ m) * 4));
        f32x4 va1 = *(const f32x4*)(xrow1 + (size_t)((L0 ^ m) * 4));
        f32x4 vb1 = *(const f32x4*)(xrow1 + (size_t)(((L0 + 1) ^ m) * 4));
        bf16x8 a0, a1;
        {
            uint32_t* p0 = (uint32_t*)&a0;
            p0[0] = cvtpk_bf16(va0[0], va0[1]);
            p0[1] = cvtpk_bf16(va0[2], va0[3]);
            p0[2] = cvtpk_bf16(vb0[0], vb0[1]);
            p0[3] = cvtpk_bf16(vb0[2], vb0[3]);
            uint32_t* p1 = (uint32_t*)&a1;
            p1[0] = cvtpk_bf16(va1[0], va1[1]);
            p1[1] = cvtpk_bf16(va1[2], va1[3]);
            p1[2] = cvtpk_bf16(vb1[0], vb1[1]);
            p1[3] = cvtpk_bf16(vb1[2], vb1[3]);
        }
#pragma unroll
        for (int t = 0; t < 3; t++) {
            int nt = ntb + t;
            // dense 1KB frag load: wtt[frag = nt*16+c][lane][8]
            bf16x8 b = *(const bf16x8*)(wt + ((size_t)(nt * 16 + c) * 64 + quad * 16 + m) * 8);
            acc0[t] = __builtin_amdgcn_mfma_f32_16x16x32_bf16(a0, b, acc0[t], 0, 0, 0);
            acc1[t] = __builtin_amdgcn_mfma_f32_16x16x32_bf16(a1, b, acc1[t], 0, 0, 0);
        }
    }

    // ---- x-copy from the LDS panel (R7 scheme) ----
#pragma unroll
    for (int k = 0; k < 16; k++) {
        int G = k * 256 + tid;
        int r = G >> 7, p = G & 127;
        f32x4 v = *(const f32x4*)(xs + (size_t)G * 4);
        int col = (p ^ (r & 15)) * 4;
        *(f32x4*)(out + (size_t)(r0b + r) * OC + col) = v;
    }
    __syncthreads();   // x-copy reads done; panel is now free for repack

    int n0 = r0b >> 12;                    // batch (blocks never straddle)
    const float SCQ = 0.125f * 1.44269504088896f;   // scale * log2(e)

    u16* qt = (u16*)xs;                    // Q tile [32][64] u16 (4 KiB)
    u16* kt = qt + 2048;                   // K tile [32][64] u16 (4 KiB)

#pragma unroll
    for (int tt = 0; tt < 2; tt++) {
        int r0 = r0b + tt * 16;
        int tl = r0 & (SEQ - 1);    // t within batch (16-aligned)
#pragma unroll
        for (int t = 0; t < 3; t++) {
            f32x4 acc = tt ? acc1[t] : acc0[t];
            int nt = ntb + t;                 // 0..11, wave-uniform
            int bi = (nt & 3) * 16 + m;       // column within its 64-wide matrix
            if (nt < 4) {
                float biasq = bq[bi];
#pragma unroll
                for (int reg = 0; reg < 4; reg++)
                    qt[(tt * 16 + quad * 4 + reg) * 64 + bi] = f2b((acc[reg] + biasq) * SCQ);
            } else if (nt < 8) {
                float biask = bk[bi];
#pragma unroll
                for (int reg = 0; reg < 4; reg++)
                    kt[(tt * 16 + quad * 4 + reg) * 64 + bi] = f2b(acc[reg] + biask);
            } else {
                // V tiled store (already contiguous): [n][bi>>4][key/32][(key>>3)&3][bi&15][key&7]
                float biasv = bv[bi];
                u16x4 pk;
#pragma unroll
                for (int reg = 0; reg < 4; reg++) pk[reg] = f2b(acc[reg] + biasv);
                int key0 = tl + quad * 4;
                size_t off = ((((size_t)(bi >> 4) * 128 + (key0 >> 5)) * 4
                               + ((key0 >> 3) & 3)) * 16 + (bi & 15)) * 8 + (key0 & 7);
                *(u16x4*)(vtb + (size_t)n0 * KVB + off) = pk;
            }
        }
    }
    __syncthreads();   // LDS tiles complete

    // coalesced Q store: thread -> (row, 8 cols) = 16B
    {
        int row = tid >> 3, c8 = (tid & 7) * 8;
        *(uint4*)(qb + (size_t)(r0b + row) * HD + c8) =
            *(const uint4*)(qt + row * 64 + c8);
    }
    // coalesced K store into the tiled layout: [n][tl/16][1024 u16] per tile.
    // global idx within tile g = (bi>>3)*128 + key*8 + (bi&7); 8 consecutive
    // g = fixed (hi,key), lo 0..7 = LDS kt[key][hi*8..+7] (contiguous both sides)
    {
        int tt2 = tid >> 7;               // row-tile 0/1
        int g = (tid & 127) * 8;          // 0..1016
        int key = (g >> 3) & 15, hi = g >> 7;
        uint4 v = *(const uint4*)(kt + (tt2 * 16 + key) * 64 + hi * 8);
        size_t gb = (size_t)n0 * KVB + ((size_t)((r0b & (SEQ - 1)) >> 4) + tt2) * 1024 + g;
        *(uint4*)(kbuf + gb) = v;
    }
}

// ---------------------------------------------------------------------------
// Kernel 3: causal flash attention. R13 = R11 EXACT (LPT map restored after
// R12's antithetic pairing regressed -> block->CU mapping assumption
// falsified) + s_setprio(1) around the MFMA clusters (T5: +4-7% measured on
// barrier-free attn structures; our visit loop has no intra-loop barriers,
// so co-resident waves are at independent phases -> scheduler can favor
// the MFMA-entering wave).
// Dense fragment-major K/V loads, union LDS, 2 q-chains, Q pre-scaled,
// l via ones-MFMA, defer-max THR=8, cvt_pk packing, launch_bounds (512,2).
// ---------------------------------------------------------------------------
__global__ __launch_bounds__(512, 2) void attn(
    const u16* __restrict__ qb, const u16* __restrict__ kbuf,
    const u16* __restrict__ vtb, float* __restrict__ out)
{
    __shared__ __align__(16) union {
        short p[8][16 * 72];     // P^T per wave (18.4 KiB) - visit phase
        float o[8][16][68];      // O^T partials (34.8 KiB) - merge phase
    } lu;
    __shared__ float ldsm[8][16];                        // m partials [w][t]
    __shared__ float ldsl[8][16];                        // l partials [w][t]

    int tid = threadIdx.x;
    int lane = tid & 63, w = tid >> 6;   // 8 waves
    int m = lane & 15, quad = lane >> 4;

    int idx = blockIdx.x;                 // 0..511
    int xcd = idx & 7;                    // HW round-robins blockIdx across XCDs
    int batch = xcd >> 1;                 // 2 XCDs per batch
    int sub = (idx >> 3) * 2 + (xcd & 1); // 0..127
    int jj = 127 - sub;                   // LPT: heavy tile first (R11)
    int t0 = jj * 32;
    int nkb = (jj >> 1) + 1;              // 64-key blocks needed
    int lastkb = nkb - 1;

    const u16* kpb = kbuf + (size_t)batch * KVB;   // tiled K base
    const u16* vpb = vtb + (size_t)batch * KVB;    // tiled V base

    bf16x8 ones;
#pragma unroll
    for (int i = 0; i < 8; i++) ones[i] = (short)0x3F80;   // bf16 1.0

    const u16* qpb = qb + (size_t)(batch * SEQ + t0 + m) * HD + quad * 8;
    bf16x8 q0[2], q1[2];
#pragma unroll
    for (int q = 0; q < 2; q++) {
        q0[q] = *(const bf16x8*)(qpb + (size_t)(q * 16) * HD);
        q1[q] = *(const bf16x8*)(qpb + (size_t)(q * 16) * HD + 32);
    }

    float mst[2];
    f32x4 o[2][4], ol[2];
#pragma unroll
    for (int q = 0; q < 2; q++) {
        mst[q] = -1e30f;
        ol[q] = (f32x4){0.f, 0.f, 0.f, 0.f};
#pragma unroll
        for (int nt = 0; nt < 4; nt++) o[q][nt] = (f32x4){0.f, 0.f, 0.f, 0.f};
    }

    int cnt = (nkb > w) ? ((nkb - w + 7) >> 3) : 0;
    int kb = w;
    short* pw = &lu.p[w][0];

    // preload K A-frags for first kb (in-bounds even when cnt==0: kb<=7)
    bf16x8 k0[4], k1[4];
#pragma unroll
    for (int st = 0; st < 4; st++) {
        k0[st] = *(const bf16x8*)(kpb + (size_t)((kb * 4 + st) * 8 + quad) * 128 + m * 8);
        k1[st] = *(const bf16x8*)(kpb + (size_t)((kb * 4 + st) * 8 + quad + 4) * 128 + m * 8);
    }

    for (int it = 0; it < cnt; it++, kb += 8) {
        int s0 = kb * 64;
        bool diag = (kb == lastkb);

        // V loads (dense 1KB frag txns), issued early, consumed after softmax
        bf16x8 vf0[4], vf1[4];
#pragma unroll
        for (int nt = 0; nt < 4; nt++) {
            vf0[nt] = *(const bf16x8*)(vpb + (size_t)((nt * 128 + (s0 >> 5)) * 4 + quad) * 128 + m * 8);
            vf1[nt] = *(const bf16x8*)(vpb + (size_t)((nt * 128 + (s0 >> 5) + 1) * 4 + quad) * 128 + m * 8);
        }

        // S^T = K Q^T for both q sub-tiles (scores pre-scaled via Q)
        f32x4 s[2][4];
        __builtin_amdgcn_s_setprio(1);
#pragma unroll
        for (int q = 0; q < 2; q++)
#pragma unroll
            for (int st = 0; st < 4; st++) {
                f32x4 a = (f32x4){0.f, 0.f, 0.f, 0.f};
                a = __builtin_amdgcn_mfma_f32_16x16x32_bf16(k0[st], q0[q], a, 0, 0, 0);
                a = __builtin_amdgcn_mfma_f32_16x16x32_bf16(k1[st], q1[q], a, 0, 0, 0);
                s[q][st] = a;
            }
        __builtin_amdgcn_s_setprio(0);

        // last K use done: prefetch next key-block for this wave
        if (it + 1 < cnt) {
            int kn = kb + 8;
#pragma unroll
            for (int st = 0; st < 4; st++) {
                k0[st] = *(const bf16x8*)(kpb + (size_t)((kn * 4 + st) * 8 + quad) * 128 + m * 8);
                k1[st] = *(const bf16x8*)(kpb + (size_t)((kn * 4 + st) * 8 + quad + 4) * 128 + m * 8);
            }
        }

        // causal mask only on the diagonal block (wave-uniform branch)
        if (diag) {
#pragma unroll
            for (int q = 0; q < 2; q++)
#pragma unroll
                for (int st = 0; st < 4; st++)
#pragma unroll
                    for (int r = 0; r < 4; r++) {
                        int key = s0 + st * 16 + quad * 4 + r;
                        if (key > t0 + q * 16 + m) s[q][st][r] = -1e30f;
                    }
        }

        // softmax + P^T pack + PV, q-chains share one P buffer (per wave)
        bf16x8 pf0[2], pf1[2];
#pragma unroll
        for (int q = 0; q < 2; q++) {
            float mx = -1e30f;
#pragma unroll
            for (int st = 0; st < 4; st++) {
                float a01 = fmaxf(s[q][st][0], s[q][st][1]);
                float a23 = fmaxf(s[q][st][2], s[q][st][3]);
                mx = fmaxf(mx, fmaxf(a01, a23));
            }
            mx = fmaxf(mx, __shfl_xor(mx, 16, 64));
            mx = fmaxf(mx, __shfl_xor(mx, 32, 64));

            // defer-max: only rescale when max grew past threshold
            if (__any(mx > mst[q] + 8.0f)) {
                float mn = fmaxf(mst[q], mx);
                float al = exp2f(mst[q] - mn);
#pragma unroll
                for (int nt = 0; nt < 4; nt++)
#pragma unroll
                    for (int r = 0; r < 4; r++) o[q][nt][r] *= al;
                ol[q][0] *= al;   // only reg 0 of ol is ever read
                mst[q] = mn;
            }

#pragma unroll
            for (int st = 0; st < 4; st++) {
                float e0 = exp2f(s[q][st][0] - mst[q]);
                float e1 = exp2f(s[q][st][1] - mst[q]);
                float e2 = exp2f(s[q][st][2] - mst[q]);
                float e3 = exp2f(s[q][st][3] - mst[q]);
                uint2 pk2;
                pk2.x = cvtpk_bf16(e0, e1);
                pk2.y = cvtpk_bf16(e2, e3);
                *(uint2*)(pw + m * 72 + st * 16 + quad * 4) = pk2;
            }
            __asm__ volatile("" ::: "memory");   // pack-writes before frag-reads
            pf0[q] = *(const bf16x8*)(pw + m * 72 + quad * 8);
            pf1[q] = *(const bf16x8*)(pw + m * 72 + 32 + quad * 8);
            __asm__ volatile("" ::: "memory");   // frag-reads before next pack
        }

        __builtin_amdgcn_s_setprio(1);
#pragma unroll
        for (int q = 0; q < 2; q++) {
            // O^T += V^T P^T ; l += ones . P^T (replaces VALU sum-reduce)
#pragma unroll
            for (int nt = 0; nt < 4; nt++) {
                o[q][nt] = __builtin_amdgcn_mfma_f32_16x16x32_bf16(vf0[nt], pf0[q], o[q][nt], 0, 0, 0);
                o[q][nt] = __builtin_amdgcn_mfma_f32_16x16x32_bf16(vf1[nt], pf1[q], o[q][nt], 0, 0, 0);
            }
            ol[q] = __builtin_amdgcn_mfma_f32_16x16x32_bf16(ones, pf0[q], ol[q], 0, 0, 0);
            ol[q] = __builtin_amdgcn_mfma_f32_16x16x32_bf16(ones, pf1[q], ol[q], 0, 0, 0);
        }
        __builtin_amdgcn_s_setprio(0);
    }

    // all waves done with lu.p before lu.o is written (union safety)
    __syncthreads();

    // merge 8 wave-partials per q sub-tile (waves with cnt==0 publish
    // m=-1e30, l=0, O=0 -> zero weight; wave 0 always has work)
#pragma unroll
    for (int q = 0; q < 2; q++) {
        if (quad == 0) { ldsm[w][m] = mst[q]; ldsl[w][m] = ol[q][0]; }
#pragma unroll
        for (int nt = 0; nt < 4; nt++)
            *(f32x4*)&lu.o[w][m][nt * 16 + quad * 4] = o[q][nt];
        __syncthreads();

        if (tid < 256) {
            int t = tid >> 4, vg = tid & 15;
            float mmax = -1e30f;
#pragma unroll
            for (int u = 0; u < 8; u++) mmax = fmaxf(mmax, ldsm[u][t]);
            float L = 0.f;
            f32x4 acc = (f32x4){0.f, 0.f, 0.f, 0.f};
#pragma unroll
            for (int u = 0; u < 8; u++) {
                float c = exp2f(ldsm[u][t] - mmax);
                L += ldsl[u][t] * c;
                f32x4 ov = *(const f32x4*)&lu.o[u][t][vg * 4];
#pragma unroll
                for (int i2 = 0; i2 < 4; i2++) acc[i2] += ov[i2] * c;
            }
            float inv = 1.0f / L;
            f32x4 res;
#pragma unroll
            for (int i2 = 0; i2 < 4; i2++) res[i2] = acc[i2] * inv;
            *(f32x4*)(out + (size_t)(batch * SEQ + t0 + q * 16 + t) * OC + CIN + vg * 4) = res;
        }
        __syncthreads();   // lu.o reused by next q
    }
}

// ---------------------------------------------------------------------------
extern "C" void kernel_launch(void* const* d_in, const int* in_sizes, int n_in,
                              void* d_out, int out_size, void* d_ws, size_t ws_size,
                              hipStream_t stream) {
    const float* x  = (const float*)d_in[0];
    const float* Wq = (const float*)d_in[1];
    const float* bq = (const float*)d_in[2];
    const float* Wk = (const float*)d_in[3];
    const float* bk = (const float*)d_in[4];
    const float* Wv = (const float*)d_in[5];
    const float* bv = (const float*)d_in[6];
    float* out = (float*)d_out;

    u16* ws  = (u16*)d_ws;
    u16* wt  = ws;                          // tiled wt: [192 frags][64 lanes][8]
    u16* qb  = ws + 131072;                 // 16384*64 = 1M elems
    u16* kb  = qb + 16384 * 64;             // tiled K: [4][256tiles][8][16][8]
    u16* vtb = kb + 16384 * 64;             // tiled V: [4][4][128][4][16][8]

    prep_wt<<<dim3(192), dim3(256), 0, stream>>>(Wq, Wk, Wv, wt);
    proj<<<dim3(512), dim3(256), 0, stream>>>(x, wt, bq, bk, bv, qb, kb, vtb, out);
    attn<<<dim3(512), dim3(512), 0, stream>>>(qb, kb, vtb, out);
}